// Round 2
// baseline (265.157 us; speedup 1.0000x reference)
//
#include <hip/hip_runtime.h>

#define DM   768
#define QKVN 2304
#define SQ   512
#define NB   16
#define NH   12

typedef unsigned short u16;
typedef _Float16 h16;
typedef _Float16 h16x8 __attribute__((ext_vector_type(8)));
typedef float f32x4 __attribute__((ext_vector_type(4)));

__device__ __forceinline__ u16 f2h(float f) {
  h16 h = (h16)f;
  return __builtin_bit_cast(u16, h);
}
__device__ __forceinline__ float h2f(u16 u) {
  return (float)__builtin_bit_cast(h16, u);
}
__device__ __forceinline__ void gload_lds16(const void* g, void* l) {
  __builtin_amdgcn_global_load_lds((__attribute__((address_space(1))) void*)(g),
                                   (__attribute__((address_space(3))) void*)(l), 16, 0, 0);
}

// ---------------- weight f32 -> fp16 convert ----------------
__global__ __launch_bounds__(256) void wconv(const float* __restrict__ src, u16* __restrict__ dst, int n) {
  int i = (blockIdx.x * 256 + threadIdx.x) * 4;
  if (i < n) {
    float4 v = *reinterpret_cast<const float4*>(src + i);
    ushort4 o;
    o.x = f2h(v.x); o.y = f2h(v.y); o.z = f2h(v.z); o.w = f2h(v.w);
    *reinterpret_cast<ushort4*>(dst + i) = o;
  }
}

// ---------------- rope cos/sin table: tab[pos*64 + 2j]=cos, +1=sin ----------------
__global__ __launch_bounds__(256) void rope_tab_k(const float* __restrict__ invf, float* __restrict__ tab) {
  int i = blockIdx.x * 256 + threadIdx.x;   // 0..16383
  int pos = i >> 5, j = i & 31;
  float a = (float)pos * invf[j];
  float s, c;
  sincosf(a, &s, &c);
  tab[i * 2] = c; tab[i * 2 + 1] = s;
}

// ---------------- RMSNorm: one wave per token (768 f32 -> fp16) ----------------
__global__ __launch_bounds__(256) void rms_k(const float* __restrict__ x, const float* __restrict__ w,
                                             u16* __restrict__ out) {
  int wv = threadIdx.x >> 6, lane = threadIdx.x & 63;
  size_t t = (size_t)blockIdx.x * 4 + wv;
  const float* row = x + t * DM;
  float4 v[3];
  float ss = 0.f;
#pragma unroll
  for (int i = 0; i < 3; i++) {
    v[i] = *reinterpret_cast<const float4*>(row + (lane + 64 * i) * 4);
    ss += v[i].x * v[i].x + v[i].y * v[i].y + v[i].z * v[i].z + v[i].w * v[i].w;
  }
#pragma unroll
  for (int d = 1; d < 64; d <<= 1) ss += __shfl_xor(ss, d);
  float rs = rsqrtf(ss * (1.0f / 768.f) + 1e-6f);
  u16* orow = out + t * DM;
#pragma unroll
  for (int i = 0; i < 3; i++) {
    int c = (lane + 64 * i) * 4;
    float4 wv4 = *reinterpret_cast<const float4*>(w + c);
    ushort4 o;
    o.x = f2h(v[i].x * rs * wv4.x);
    o.y = f2h(v[i].y * rs * wv4.y);
    o.z = f2h(v[i].z * rs * wv4.z);
    o.w = f2h(v[i].w * rs * wv4.w);
    *reinterpret_cast<ushort4*>(orow + c) = o;
  }
}

// ---------------- GEMM: C[M=8192,N] = A[M,768] * W[N,768]^T (both fp16, K-major) ----------------
// 128x128 tile, BK=64, 4 waves (2x2), 16x16x32 MFMA. LDS linear + XOR-swizzled global source.
template <bool RESID>
__global__ __launch_bounds__(256) void gemm_k(const u16* __restrict__ A, const u16* __restrict__ W, int N,
                                              u16* __restrict__ Cb, float* __restrict__ Cf,
                                              const float* __restrict__ resid) {
  __shared__ u16 Al[128 * 64];
  __shared__ u16 Bl[128 * 64];
  const int tid = threadIdx.x, w = tid >> 6, lane = tid & 63;
  const int wr = w >> 1, wc = w & 1;
  const int bm = blockIdx.x, bnb = blockIdx.y;
  const int l15 = lane & 15, l4 = lane >> 4;
  f32x4 acc[4][4] = {};
  const int srow = lane >> 3;        // 0..7
  const int scol = (lane & 7) * 16;  // byte within 128B row chunk

  for (int kt = 0; kt < 12; ++kt) {
    __syncthreads();
#pragma unroll
    for (int e = 0; e < 4; e++) {
      int rr = w * 32 + e * 8;
      int r = rr + srow;
      int off = scol ^ ((r & 7) << 4);
      gload_lds16((const char*)A + (size_t)(bm * 128 + r) * 1536 + kt * 128 + off, (char*)Al + rr * 128);
      gload_lds16((const char*)W + (size_t)(bnb * 128 + r) * 1536 + kt * 128 + off, (char*)Bl + rr * 128);
    }
    __syncthreads();
#pragma unroll
    for (int kk = 0; kk < 2; kk++) {
      h16x8 am[4], bn[4];
#pragma unroll
      for (int i = 0; i < 4; i++) {
        int row = wr * 64 + i * 16 + l15;
        int off = (kk * 64 + 16 * l4) ^ ((row & 7) << 4);
        am[i] = *reinterpret_cast<const h16x8*>((const char*)Al + row * 128 + off);
      }
#pragma unroll
      for (int j = 0; j < 4; j++) {
        int row = wc * 64 + j * 16 + l15;
        int off = (kk * 64 + 16 * l4) ^ ((row & 7) << 4);
        bn[j] = *reinterpret_cast<const h16x8*>((const char*)Bl + row * 128 + off);
      }
#pragma unroll
      for (int i = 0; i < 4; i++)
#pragma unroll
        for (int j = 0; j < 4; j++)
          acc[i][j] = __builtin_amdgcn_mfma_f32_16x16x32_f16(am[i], bn[j], acc[i][j], 0, 0, 0);
    }
  }
#pragma unroll
  for (int i = 0; i < 4; i++) {
    int row0 = bm * 128 + wr * 64 + i * 16 + l4 * 4;
#pragma unroll
    for (int j = 0; j < 4; j++) {
      int col = bnb * 128 + wc * 64 + j * 16 + l15;
#pragma unroll
      for (int r = 0; r < 4; r++) {
        size_t idx = (size_t)(row0 + r) * N + col;
        float v = acc[i][j][r];
        if (RESID) Cf[idx] = v + resid[idx];
        else Cb[idx] = f2h(v);
      }
    }
  }
}

// ---------------- RoPE in-place on Q,K halves of qkv ----------------
__global__ __launch_bounds__(192) void rope_k(u16* __restrict__ qkv, const int* __restrict__ pids,
                                              const float* __restrict__ tab) {
  const int t = blockIdx.x;
  const int tid = threadIdx.x;
  const int pos = pids[t];
  const int isK = tid >= 96;
  const int c = isK ? tid - 96 : tid;
  const int head = c >> 3, d0 = (c & 7) * 4;  // d0 in [0,28], pairs (d0+i, d0+i+32)
  u16* p = qkv + (size_t)t * QKVN + (isK ? DM : 0) + head * 64 + d0;
  ushort4 lo = *reinterpret_cast<ushort4*>(p);
  ushort4 hi = *reinterpret_cast<ushort4*>(p + 32);
  const float* tb = tab + pos * 64 + d0 * 2;
  float4 cs0 = *reinterpret_cast<const float4*>(tb);
  float4 cs1 = *reinterpret_cast<const float4*>(tb + 4);
  float lv[4] = {h2f(lo.x), h2f(lo.y), h2f(lo.z), h2f(lo.w)};
  float hv[4] = {h2f(hi.x), h2f(hi.y), h2f(hi.z), h2f(hi.w)};
  float cc[4] = {cs0.x, cs0.z, cs1.x, cs1.z};
  float sn[4] = {cs0.y, cs0.w, cs1.y, cs1.w};
  ushort4 olo, ohi;
  olo.x = f2h(lv[0] * cc[0] - hv[0] * sn[0]); ohi.x = f2h(hv[0] * cc[0] + lv[0] * sn[0]);
  olo.y = f2h(lv[1] * cc[1] - hv[1] * sn[1]); ohi.y = f2h(hv[1] * cc[1] + lv[1] * sn[1]);
  olo.z = f2h(lv[2] * cc[2] - hv[2] * sn[2]); ohi.z = f2h(hv[2] * cc[2] + lv[2] * sn[2]);
  olo.w = f2h(lv[3] * cc[3] - hv[3] * sn[3]); ohi.w = f2h(hv[3] * cc[3] + lv[3] * sn[3]);
  *reinterpret_cast<ushort4*>(p) = olo;
  *reinterpret_cast<ushort4*>(p + 32) = ohi;
}

// ---------------- Pass-1 attention: causal flash over S, per (qtile, b, h) ----------------
__global__ __launch_bounds__(256) void attn1_k(const u16* __restrict__ qkv, const float* __restrict__ mask,
                                               u16* __restrict__ O) {
  __shared__ u16 Kl[64 * 64];
  __shared__ u16 Vt[64 * 64];
  __shared__ u16 Pl[4][16 * 64];
  const int qt = blockIdx.x;   // 0..7
  const int bh = blockIdx.y;   // 0..191
  const int b = bh / NH, h = bh % NH;
  const int tid = threadIdx.x, w = tid >> 6, lane = tid & 63;
  const int l15 = lane & 15, l4 = lane >> 4;
  // Q fragments (A-operand rows = l15)
  const size_t qoff = ((size_t)(b * SQ + qt * 64 + w * 16 + l15)) * QKVN + h * 64;
  h16x8 qf[2];
  qf[0] = *reinterpret_cast<const h16x8*>(qkv + qoff + 8 * l4);
  qf[1] = *reinterpret_cast<const h16x8*>(qkv + qoff + 32 + 8 * l4);
  f32x4 acco[4] = {};
  float mrun[4] = {-3e38f, -3e38f, -3e38f, -3e38f};
  float lrun[4] = {0.f, 0.f, 0.f, 0.f};
  const float* mbase = mask + (size_t)bh * SQ * SQ;
  const int qa0 = qt * 64 + w * 16 + l4 * 4;  // accumulator row base (q)

  for (int kt = 0; kt <= qt; ++kt) {  // causal skip: future tiles are exactly exp(-1e9)->0
    __syncthreads();
    // K tile -> LDS (swizzled source, linear dest)
#pragma unroll
    for (int e = 0; e < 2; e++) {
      int rr = (w * 2 + e) * 8;
      int r = rr + (lane >> 3);
      int off = ((lane & 7) * 16) ^ ((r & 7) << 4);
      gload_lds16((const char*)qkv + ((size_t)(b * SQ + kt * 64 + r) * QKVN + DM + h * 64) * 2 + off,
                  (char*)Kl + rr * 128);
    }
    // V tile transposed -> LDS (reg-staged, swizzled scalar writes)
    {
      int key = tid >> 2, d0 = (tid & 3) * 16;
      const u16* vsrc = qkv + (size_t)(b * SQ + kt * 64 + key) * QKVN + 2 * DM + h * 64 + d0;
      ushort4 a0 = *reinterpret_cast<const ushort4*>(vsrc + 0);
      ushort4 a1 = *reinterpret_cast<const ushort4*>(vsrc + 4);
      ushort4 a2 = *reinterpret_cast<const ushort4*>(vsrc + 8);
      ushort4 a3 = *reinterpret_cast<const ushort4*>(vsrc + 12);
      u16 vals[16] = {a0.x, a0.y, a0.z, a0.w, a1.x, a1.y, a1.z, a1.w,
                      a2.x, a2.y, a2.z, a2.w, a3.x, a3.y, a3.z, a3.w};
#pragma unroll
      for (int i = 0; i < 16; i++) {
        int d = d0 + i;
        int byte = d * 128 + ((2 * key) ^ ((d & 7) << 4));
        *(u16*)((char*)Vt + byte) = vals[i];
      }
    }
    __syncthreads();
    // scores = Q K^T  (D: col=key=l15+16j, row=q=l4*4+r)
    f32x4 sc[4] = {};
#pragma unroll
    for (int kk = 0; kk < 2; kk++) {
#pragma unroll
      for (int j = 0; j < 4; j++) {
        int row = j * 16 + l15;
        int off = (kk * 64 + 16 * l4) ^ ((row & 7) << 4);
        h16x8 kf = *reinterpret_cast<const h16x8*>((const char*)Kl + row * 128 + off);
        sc[j] = __builtin_amdgcn_mfma_f32_16x16x32_f16(qf[kk], kf, sc[j], 0, 0, 0);
      }
    }
    // mask add + online softmax (row reduce across lanes 0..15 of each group)
    float pv[4][4];
#pragma unroll
    for (int r = 0; r < 4; r++) {
      const float* mrow = mbase + (size_t)(qa0 + r) * SQ + kt * 64 + l15;
#pragma unroll
      for (int j = 0; j < 4; j++) pv[j][r] = sc[j][r] + mrow[j * 16];
    }
    float al[4];
#pragma unroll
    for (int r = 0; r < 4; r++) {
      float tm = fmaxf(fmaxf(pv[0][r], pv[1][r]), fmaxf(pv[2][r], pv[3][r]));
      tm = fmaxf(tm, __shfl_xor(tm, 1)); tm = fmaxf(tm, __shfl_xor(tm, 2));
      tm = fmaxf(tm, __shfl_xor(tm, 4)); tm = fmaxf(tm, __shfl_xor(tm, 8));
      float mn = fmaxf(mrun[r], tm);
      al[r] = __expf(mrun[r] - mn);
      mrun[r] = mn;
      float ts = 0.f;
#pragma unroll
      for (int j = 0; j < 4; j++) { float p = __expf(pv[j][r] - mn); pv[j][r] = p; ts += p; }
      ts += __shfl_xor(ts, 1); ts += __shfl_xor(ts, 2); ts += __shfl_xor(ts, 4); ts += __shfl_xor(ts, 8);
      lrun[r] = lrun[r] * al[r] + ts;
    }
#pragma unroll
    for (int j = 0; j < 4; j++)
#pragma unroll
      for (int r = 0; r < 4; r++) acco[j][r] *= al[r];
    // P -> per-wave LDS (transpose for A-operand), fp16, swizzled
    u16* pw = Pl[w];
#pragma unroll
    for (int r = 0; r < 4; r++) {
      int q = l4 * 4 + r;
      int sw = (q & 7) << 4;
#pragma unroll
      for (int j = 0; j < 4; j++) {
        int byte = q * 128 + ((2 * (j * 16 + l15)) ^ sw);
        *(u16*)((char*)pw + byte) = f2h(pv[j][r]);
      }
    }
    asm volatile("s_waitcnt lgkmcnt(0)" ::: "memory");
    __builtin_amdgcn_sched_barrier(0);
    // out += P V
#pragma unroll
    for (int kk = 0; kk < 2; kk++) {
      int poff = (kk * 64 + 16 * l4) ^ ((l15 & 7) << 4);
      h16x8 pa = *reinterpret_cast<const h16x8*>((const char*)pw + l15 * 128 + poff);
#pragma unroll
      for (int j = 0; j < 4; j++) {
        int d = j * 16 + l15;
        int voff = (kk * 64 + 16 * l4) ^ ((d & 7) << 4);
        h16x8 vf = *reinterpret_cast<const h16x8*>((const char*)Vt + d * 128 + voff);
        acco[j] = __builtin_amdgcn_mfma_f32_16x16x32_f16(pa, vf, acco[j], 0, 0, 0);
      }
    }
  }
  // normalize + store
#pragma unroll
  for (int r = 0; r < 4; r++) {
    float inv = 1.f / lrun[r];
    size_t orow = ((size_t)(b * SQ + qa0 + r)) * DM + h * 64;
#pragma unroll
    for (int j = 0; j < 4; j++) O[orow + j * 16 + l15] = f2h(acco[j][r] * inv);
  }
}

// ---------------- Pass-2 attention: 16x16 per (s,h), one wave each ----------------
__global__ __launch_bounds__(256) void attn2_k(const u16* __restrict__ qkv, const float* __restrict__ gmask,
                                               u16* __restrict__ O) {
  __shared__ float Pl[4][16][16];
  __shared__ float Vl[4][16][68];
  const int tid = threadIdx.x, w = tid >> 6, lane = tid & 63;
  const int idx = blockIdx.x * 4 + w;
  const int s = idx / NH, h = idx % NH;
  const int l15 = lane & 15, l4 = lane >> 4;
  const size_t base = ((size_t)l15 * SQ + s) * QKVN + h * 64;
  h16x8 qf0 = *reinterpret_cast<const h16x8*>(qkv + base + 8 * l4);
  h16x8 qf1 = *reinterpret_cast<const h16x8*>(qkv + base + 32 + 8 * l4);
  h16x8 kf0 = *reinterpret_cast<const h16x8*>(qkv + base + DM + 8 * l4);
  h16x8 kf1 = *reinterpret_cast<const h16x8*>(qkv + base + DM + 32 + 8 * l4);
  f32x4 sc = {};
  sc = __builtin_amdgcn_mfma_f32_16x16x32_f16(qf0, kf0, sc, 0, 0, 0);
  sc = __builtin_amdgcn_mfma_f32_16x16x32_f16(qf1, kf1, sc, 0, 0, 0);
  // stage V (f32) per wave: lane -> (key=lane>>2, 16 dims)
  {
    int key = lane >> 2, d0 = (lane & 3) * 16;
    const u16* vsrc = qkv + ((size_t)key * SQ + s) * QKVN + 2 * DM + h * 64 + d0;
#pragma unroll
    for (int i = 0; i < 16; i += 4) {
      ushort4 vv = *reinterpret_cast<const ushort4*>(vsrc + i);
      Vl[w][key][d0 + i + 0] = h2f(vv.x);
      Vl[w][key][d0 + i + 1] = h2f(vv.y);
      Vl[w][key][d0 + i + 2] = h2f(vv.z);
      Vl[w][key][d0 + i + 3] = h2f(vv.w);
    }
  }
  const float* gm = gmask + ((size_t)s * NH + h) * 256;
#pragma unroll
  for (int r = 0; r < 4; r++) {
    float v = sc[r] + gm[(l4 * 4 + r) * 16 + l15];
    float mx = v;
    mx = fmaxf(mx, __shfl_xor(mx, 1)); mx = fmaxf(mx, __shfl_xor(mx, 2));
    mx = fmaxf(mx, __shfl_xor(mx, 4)); mx = fmaxf(mx, __shfl_xor(mx, 8));
    float p = __expf(v - mx);
    float su = p;
    su += __shfl_xor(su, 1); su += __shfl_xor(su, 2); su += __shfl_xor(su, 4); su += __shfl_xor(su, 8);
    Pl[w][l4 * 4 + r][l15] = p / su;
  }
  asm volatile("s_waitcnt lgkmcnt(0)" ::: "memory");
  __builtin_amdgcn_sched_barrier(0);
  // PV on VALU: lane -> (q=lane>>2, 16 dims)
  const int q = lane >> 2, d0 = (lane & 3) * 16;
  float o[16] = {};
#pragma unroll
  for (int key = 0; key < 16; key++) {
    float pp = Pl[w][q][key];
#pragma unroll
    for (int dd = 0; dd < 16; dd += 4) {
      float4 vv = *reinterpret_cast<const float4*>(&Vl[w][key][d0 + dd]);
      o[dd + 0] += pp * vv.x; o[dd + 1] += pp * vv.y; o[dd + 2] += pp * vv.z; o[dd + 3] += pp * vv.w;
    }
  }
  u16* orow = O + ((size_t)q * SQ + s) * DM + h * 64 + d0;
#pragma unroll
  for (int i = 0; i < 16; i += 4) {
    ushort4 ov;
    ov.x = f2h(o[i]); ov.y = f2h(o[i + 1]); ov.z = f2h(o[i + 2]); ov.w = f2h(o[i + 3]);
    *reinterpret_cast<ushort4*>(orow + i) = ov;
  }
}

// ---------------- launch ----------------
extern "C" void kernel_launch(void* const* d_in, const int* in_sizes, int n_in,
                              void* d_out, int out_size, void* d_ws, size_t ws_size,
                              hipStream_t stream) {
  const float* hidden = (const float*)d_in[0];
  const int*   pids   = (const int*)d_in[1];
  const float* amask  = (const float*)d_in[2];
  const float* gmask  = (const float*)d_in[3];
  const float* tq = (const float*)d_in[4];
  const float* tk = (const float*)d_in[5];
  const float* tv = (const float*)d_in[6];
  const float* to_ = (const float*)d_in[7];
  const float* tnw = (const float*)d_in[8];
  const float* gq = (const float*)d_in[9];
  const float* gk = (const float*)d_in[10];
  const float* gv = (const float*)d_in[11];
  const float* go = (const float*)d_in[12];
  const float* gnw = (const float*)d_in[13];
  const float* invf = (const float*)d_in[14];
  float* out = (float*)d_out;
  char* ws = (char*)d_ws;

  u16*   wq1    = (u16*)(ws);                   // 2304x768 fp16
  u16*   wo1    = (u16*)(ws + 3538944);         // 768x768
  u16*   wq2    = (u16*)(ws + 4718592);
  u16*   wo2    = (u16*)(ws + 8257536);
  float* tab    = (float*)(ws + 9437184);       // 512x32x2 f32
  u16*   normed = (u16*)(ws + 9568256);         // 8192x768 fp16
  u16*   obuf   = (u16*)(ws + 22151168);        // 8192x768 fp16
  float* h1     = (float*)(ws + 34734080);      // 8192x768 f32
  u16*   qkv    = (u16*)(ws + 59899904);        // 8192x2304 fp16

  const int WN = 768 * 768;
  wconv<<<576, 256, 0, stream>>>(tq, wq1, WN);
  wconv<<<576, 256, 0, stream>>>(tk, wq1 + WN, WN);
  wconv<<<576, 256, 0, stream>>>(tv, wq1 + 2 * WN, WN);
  wconv<<<576, 256, 0, stream>>>(to_, wo1, WN);
  wconv<<<576, 256, 0, stream>>>(gq, wq2, WN);
  wconv<<<576, 256, 0, stream>>>(gk, wq2 + WN, WN);
  wconv<<<576, 256, 0, stream>>>(gv, wq2 + 2 * WN, WN);
  wconv<<<576, 256, 0, stream>>>(go, wo2, WN);
  rope_tab_k<<<64, 256, 0, stream>>>(invf, tab);

  // pass 1 (time attention, causal + RoPE)
  rms_k<<<2048, 256, 0, stream>>>(hidden, tnw, normed);
  gemm_k<false><<<dim3(64, 18), 256, 0, stream>>>(normed, wq1, QKVN, qkv, nullptr, nullptr);
  rope_k<<<8192, 192, 0, stream>>>(qkv, pids, tab);
  attn1_k<<<dim3(8, 192), 256, 0, stream>>>(qkv, amask, obuf);
  gemm_k<true><<<dim3(64, 6), 256, 0, stream>>>(obuf, wo1, DM, nullptr, h1, hidden);

  // pass 2 (group attention over batch dim; logical transpose via indexing)
  rms_k<<<2048, 256, 0, stream>>>(h1, gnw, normed);
  gemm_k<false><<<dim3(64, 18), 256, 0, stream>>>(normed, wq2, QKVN, qkv, nullptr, nullptr);
  attn2_k<<<1536, 256, 0, stream>>>(qkv, gmask, obuf);
  gemm_k<true><<<dim3(64, 6), 256, 0, stream>>>(obuf, wo2, DM, nullptr, out, h1);
}